// Round 8
// baseline (570.220 us; speedup 1.0000x reference)
//
#include <hip/hip_runtime.h>
#include <math.h>

// ---- problem constants ----
constexpr int Bc = 4, Lc = 2048, Kc = 30;
constexpr int Nn = Bc * Lc;            // 8192 nodes
constexpr int NSc = 1024, NVc = 256;
constexpr int NEc = Nn * Kc;           // 245760 edges
constexpr int SK = 263;                // 7 + 256 scalar GVP input dim

// ---- d_out float offsets (outputs concatenated flat in return order) ----
constexpr size_t OUT_NS = 0;                                  // (8192,1024)
constexpr size_t OUT_NV = (size_t)Nn * NSc;                   // (8192,256,3)
constexpr size_t OUT_ES = OUT_NV + (size_t)Nn * NVc * 3;      // (245760,32)
constexpr size_t OUT_EV = OUT_ES + (size_t)NEc * 32;          // (245760,1,3)
constexpr size_t OUT_EI = OUT_EV + (size_t)NEc * 3;           // (2,245760) as float

// ---- workspace float offsets ----
constexpr size_t WS_SIN = 0;                                  // (8192,263) s_in
constexpr size_t WS_NDV = WS_SIN + (size_t)Nn * SK;           // (8192,9) node_v
constexpr size_t WS_EIX = WS_NDV + (size_t)Nn * 9;            // (245760) int E_idx
constexpr size_t WS_EDS = WS_EIX + (size_t)NEc;               // (245760) E_dist
constexpr size_t WS_CMF = WS_EDS + (size_t)NEc;               // (8192) canonical coord_mask float

__device__ __forceinline__ void norml3(float& x, float& y, float& z) {
  float ss = x*x + y*y + z*z;
  float inv = 1.0f / sqrtf(ss + 1e-8f);
  x *= inv; y *= inv; z *= inv;
}

// ---------------- Kernel M: canonicalize coord_mask (bytes-vs-int32 autodetect) ----
__global__ __launch_bounds__(256) void kmask(const unsigned char* __restrict__ cm,
                                             float* __restrict__ ws) {
  __shared__ int flag;
  if (threadIdx.x == 0) flag = 0;
  __syncthreads();
  int any = 0;
  for (int p = threadIdx.x; p < 1024; p += 256)
    if (p & 3) any |= cm[p];
  if (any) atomicOr(&flag, 1);
  __syncthreads();
  bool bytefmt = (flag != 0);
  int n = blockIdx.x * 256 + threadIdx.x;
  unsigned char v = bytefmt ? cm[n] : cm[4*n];  // LE low byte of int32 0/1
  ws[WS_CMF + n] = v ? 1.f : 0.f;
}

// ---------------- Kernel A: per-node geometric features ----------------
__global__ __launch_bounds__(256) void knode_geom(const float* __restrict__ coords,
                                                  float* __restrict__ ws) {
  int n = blockIdx.x * 256 + threadIdx.x;
  if (n >= Nn) return;
  int b = n / Lc, l = n % Lc;
  const float* Xb = coords + (size_t)b * Lc * 9;
  float ax[7][3];
  #pragma unroll
  for (int m = 0; m < 7; ++m) {
    int t = 3*l + m - 2;
    if (t >= 0 && t < 3*Lc) { ax[m][0]=Xb[t*3+0]; ax[m][1]=Xb[t*3+1]; ax[m][2]=Xb[t*3+2]; }
    else { ax[m][0]=0.f; ax[m][1]=0.f; ax[m][2]=0.f; }
  }
  float U[5][3];
  #pragma unroll
  for (int mi = 0; mi < 5; ++mi) {
    int t = 3*l - 1 + mi;
    if (t >= 0 && t <= 3*Lc - 2) {
      float x = ax[mi+2][0]-ax[mi+1][0], y = ax[mi+2][1]-ax[mi+1][1], z = ax[mi+2][2]-ax[mi+1][2];
      norml3(x,y,z);
      U[mi][0]=x; U[mi][1]=y; U[mi][2]=z;
    } else { U[mi][0]=0.f; U[mi][1]=0.f; U[mi][2]=0.f; }
  }
  float cph[3], sph[3];
  #pragma unroll
  for (int a = 0; a < 3; ++a) {
    int t = 3*l + a - 1;
    if (t < 0 || t > 3*Lc - 4) { cph[a] = 1.f; sph[a] = 0.f; continue; }
    const float *u2 = U[a], *u1 = U[a+1], *u0 = U[a+2];
    float n2x = u2[1]*u1[2]-u2[2]*u1[1], n2y = u2[2]*u1[0]-u2[0]*u1[2], n2z = u2[0]*u1[1]-u2[1]*u1[0];
    norml3(n2x,n2y,n2z);
    float n1x = u1[1]*u0[2]-u1[2]*u0[1], n1y = u1[2]*u0[0]-u1[0]*u0[2], n1z = u1[0]*u0[1]-u1[1]*u0[0];
    norml3(n1x,n1y,n1z);
    float cd = n2x*n1x + n2y*n1y + n2z*n1z;
    cd = fminf(fmaxf(cd, -1.f + 1e-7f), 1.f - 1e-7f);
    float dt = u2[0]*n1x + u2[1]*n1y + u2[2]*n1z;
    float sg = (dt > 0.f) ? 1.f : ((dt < 0.f) ? -1.f : 0.f);
    float D = sg * acosf(cd);
    cph[a] = cosf(D); sph[a] = sinf(D);
  }
  float fx=0.f,fy=0.f,fz=0.f, kx=0.f,ky=0.f,kz=0.f;
  if (l < Lc-1) { fx=ax[6][0]-ax[3][0]; fy=ax[6][1]-ax[3][1]; fz=ax[6][2]-ax[3][2]; norml3(fx,fy,fz); }
  if (l > 0)    { kx=ax[0][0]-ax[3][0]; ky=ax[0][1]-ax[3][1]; kz=ax[0][2]-ax[3][2]; norml3(kx,ky,kz); }
  float cx=ax[4][0]-ax[3][0], cy=ax[4][1]-ax[3][1], cz=ax[4][2]-ax[3][2]; norml3(cx,cy,cz);
  float nx=ax[2][0]-ax[3][0], ny=ax[2][1]-ax[3][1], nz=ax[2][2]-ax[3][2]; norml3(nx,ny,nz);
  float bix=cx+nx, biy=cy+ny, biz=cz+nz; norml3(bix,biy,biz);
  float px=cy*nz-cz*ny, py=cz*nx-cx*nz, pz=cx*ny-cy*nx; norml3(px,py,pz);
  const float c1 = 0.57735026f, c2 = 0.81649658f;
  float sx = -bix*c1 - px*c2, sy = -biy*c1 - py*c2, sz = -biz*c1 - pz*c2;

  float cmf = ws[WS_CMF + n];
  float* sr = ws + WS_SIN + (size_t)n * SK;
  sr[0]=cph[0]; sr[1]=cph[1]; sr[2]=cph[2]; sr[3]=sph[0]; sr[4]=sph[1]; sr[5]=sph[2]; sr[6]=cmf;
  float* vr = ws + WS_NDV + (size_t)n * 9;
  vr[0]=fx; vr[1]=fy; vr[2]=fz; vr[3]=kx; vr[4]=ky; vr[5]=kz; vr[6]=sx; vr[7]=sy; vr[8]=sz;
}

// ---------------- Kernel D1: vh + vn + conf-RBF precompute ----------------
__global__ __launch_bounds__(256) void kgvp_pre(float* __restrict__ ws,
                                                const float* __restrict__ wh,
                                                const float* __restrict__ conf,
                                                float* __restrict__ avh,
                                                float* __restrict__ rbuf) {
  int n = blockIdx.x, h = threadIdx.x;
  const float* v = ws + WS_NDV + (size_t)n * 9;
  float w0 = wh[h], w1 = wh[256+h], w2 = wh[512+h];
  float vh0 = v[0]*w0 + v[3]*w1 + v[6]*w2;
  float vh1 = v[1]*w0 + v[4]*w1 + v[7]*w2;
  float vh2 = v[2]*w0 + v[5]*w1 + v[8]*w2;
  avh[(size_t)0*Nn*256 + (size_t)n*256 + h] = vh0;
  avh[(size_t)1*Nn*256 + (size_t)n*256 + h] = vh1;
  avh[(size_t)2*Nn*256 + (size_t)n*256 + h] = vh2;
  ws[WS_SIN + (size_t)n*SK + 7 + h] = sqrtf(fmaxf(vh0*vh0 + vh1*vh1 + vh2*vh2, 1e-8f));
  if (h < 16) {
    float z = (conf[n] - (float)h*(1.f/15.f)) * 16.f;   // std = 1/16
    rbuf[(size_t)n*16 + h] = expf(-z*z);
  }
}

// ---------------- Kernel B: wave-autonomous exact top-30 radix select ----------
// 8 rows/block (grid 1024 -> 4 blocks/CU), 2 rows/wave. Per-candidate key is
// u32 adj-bits only (j = lane+64*m implicit) -> ~32 fewer VGPRs. hist and cbuf
// share one 1.5KB/wave LDS union. Order = (adj_bits, j), lowest-index ties.
__global__ __launch_bounds__(256) void ktopk(const float* __restrict__ coords,
                                             const int* __restrict__ resid,
                                             const unsigned char* __restrict__ pmask,
                                             float* __restrict__ ws) {
  __shared__ float xsx[Lc], xsy[Lc], xsz[Lc];
  __shared__ int   res[Lc];
  __shared__ unsigned cmw[Lc/32], rmw[Lc/32];
  __shared__ __align__(16) unsigned long long wbuf[4][192];   // union: hist(1KB) | cbuf(1.5KB)
  int tid = threadIdx.x, lane = tid & 63, wid = tid >> 6;
  int row0 = blockIdx.x * 8;
  int b = row0 >> 11;
  int i0 = row0 & (Lc - 1);
  const float* Xb = coords + (size_t)b * Lc * 9;
  for (int it = 0; it < Lc/256; ++it) {
    int j = tid + 256*it;
    xsx[j] = Xb[j*9+3]; xsy[j] = Xb[j*9+4]; xsz[j] = Xb[j*9+5];
    res[j] = resid[b*Lc + j];
    unsigned long long mcm = __ballot(ws[WS_CMF + b*Lc + j] != 0.f);
    unsigned long long mrm = __ballot(pmask[b*Lc + j] == 0);
    if (lane == 0) {
      int w0 = j >> 5;
      cmw[w0] = (unsigned)mcm; cmw[w0+1] = (unsigned)(mcm >> 32);
      rmw[w0] = (unsigned)mrm; rmw[w0+1] = (unsigned)(mrm >> 32);
    }
  }
  __syncthreads();
  int* eix = (int*)(ws + WS_EIX);
  unsigned long long lmask_lt = (1ULL << lane) - 1ULL;
  unsigned* hist = (unsigned*)&wbuf[wid][0];
  for (int rr = 0; rr < 2; ++rr) {
    int i = i0 + wid*2 + rr;
    int row = row0 + wid*2 + rr;
    float xi0 = xsx[i], xi1 = xsy[i], xi2 = xsz[i];
    float cmi = ((cmw[i>>5] >> (i&31)) & 1) ? 1.f : 0.f;
    float rmi = ((rmw[i>>5] >> (i&31)) & 1) ? 1.f : 0.f;
    int ri = res[i];
    unsigned keyf[32];
    #pragma unroll
    for (int m = 0; m < 32; ++m) {
      int j = lane + 64*m;
      float cmj = ((cmw[j>>5] >> (j&31)) & 1) ? 1.f : 0.f;
      float rmj = ((rmw[j>>5] >> (j&31)) & 1) ? 1.f : 0.f;
      float dx = __fsub_rn(xi0, xsx[j]);
      float dy = __fsub_rn(xi1, xsy[j]);
      float dz = __fsub_rn(xi2, xsz[j]);
      float ss = __fadd_rn(__fadd_rn(__fmul_rn(dx,dx), __fmul_rn(dy,dy)), __fmul_rn(dz,dz));
      float dist = __fsqrt_rn(__fadd_rn(ss, 1e-8f));
      float cm2 = __fmul_rn(cmi, cmj);
      float D = __fmul_rn(cm2, dist);
      int ad = ri - res[j]; ad = ad < 0 ? -ad : ad;
      float covm = (ad <= 3) ? 0.f : 1.f;
      float dseq = (float)(i >= j ? i - j : j - i);
      float t1 = __fmul_rn(__fsub_rn(1.f, cm2), __fadd_rn(1e8f, __fmul_rn(dseq, 1e6f)));
      float rm2 = __fmul_rn(rmi, rmj);
      float t2 = __fmul_rn(__fsub_rn(1.f, rm2), 1e10f);
      float adj = __fadd_rn(__fadd_rn(__fmul_rn(D, covm), t1), t2);
      keyf[m] = __float_as_uint(adj);
    }
    unsigned cut16;
    {
      // ---- level-1: 256-bin histogram on adj bits [31:24] ----
      *(uint4*)&hist[lane*4] = uint4{0u,0u,0u,0u};
      __builtin_amdgcn_wave_barrier();
      #pragma unroll
      for (int m = 0; m < 32; ++m) atomicAdd(&hist[keyf[m] >> 24], 1u);
      __builtin_amdgcn_wave_barrier();
      uint4 hq = *(const uint4*)&hist[lane*4];
      unsigned h0 = hq.x, h1 = hq.y, h2 = hq.z, h3 = hq.w;
      unsigned s = h0+h1+h2+h3;
      unsigned v = s;
      #pragma unroll
      for (int off = 1; off < 64; off <<= 1) { unsigned o = __shfl_up(v, off); if (lane >= off) v += o; }
      unsigned excl = v - s;
      unsigned target = Kc;
      unsigned inc0 = excl+h0, inc1 = inc0+h1, inc2 = inc1+h2, inc3 = inc2+h3;
      bool cross = (inc3 >= target) && (excl < target);
      unsigned cb, nb;
      if      (inc0 >= target) { cb = 0; nb = excl; }
      else if (inc1 >= target) { cb = 1; nb = inc0; }
      else if (inc2 >= target) { cb = 2; nb = inc1; }
      else                     { cb = 3; nb = inc2; }
      int src = __ffsll((long long)__ballot(cross)) - 1;
      if (src < 0) src = 0;
      unsigned c1  = __shfl((unsigned)(lane*4) + cb, src);
      unsigned nb1 = __shfl(nb, src);
      // ---- level-2: histogram on adj bits [23:16] within bin c1 ----
      *(uint4*)&hist[lane*4] = uint4{0u,0u,0u,0u};
      __builtin_amdgcn_wave_barrier();
      #pragma unroll
      for (int m = 0; m < 32; ++m)
        if ((keyf[m] >> 24) == c1) atomicAdd(&hist[(keyf[m] >> 16) & 0xFF], 1u);
      __builtin_amdgcn_wave_barrier();
      hq = *(const uint4*)&hist[lane*4];
      h0 = hq.x; h1 = hq.y; h2 = hq.z; h3 = hq.w;
      s = h0+h1+h2+h3;
      v = s;
      #pragma unroll
      for (int off = 1; off < 64; off <<= 1) { unsigned o = __shfl_up(v, off); if (lane >= off) v += o; }
      excl = v - s;
      target = Kc - nb1;
      inc0 = excl+h0; inc1 = inc0+h1; inc2 = inc1+h2; inc3 = inc2+h3;
      cross = (inc3 >= target) && (excl < target);
      if      (inc0 >= target) cb = 0;
      else if (inc1 >= target) cb = 1;
      else if (inc2 >= target) cb = 2;
      else                     cb = 3;
      src = __ffsll((long long)__ballot(cross)) - 1;
      if (src < 0) src = 0;
      cut16 = __shfl((c1 << 8) | ((unsigned)(lane*4) + cb), src);
    }
    __builtin_amdgcn_wave_barrier();            // hist dead, cbuf reuses the space
    // ---- compact keys with hi16 <= cut16 via deterministic ballot prefix ----
    unsigned base = 0;
    #pragma unroll
    for (int m = 0; m < 32; ++m) {
      bool pred = ((keyf[m] >> 16) <= cut16);
      unsigned long long bal = __ballot(pred);
      if (pred) {
        unsigned pos = base + (unsigned)__popcll(bal & lmask_lt);
        if (pos < 192u)
          wbuf[wid][pos] = ((unsigned long long)keyf[m] << 32) | (unsigned)(lane + 64*m);
      }
      base += (unsigned)__popcll(bal);
    }
    unsigned M = base < 192u ? base : 192u;
    __builtin_amdgcn_wave_barrier();
    // ---- rank by counting among compacted candidates, emit top-Kc ----
    for (unsigned idx = (unsigned)lane; idx < M; idx += 64u) {
      unsigned long long k0 = wbuf[wid][idx];
      int rank = 0;
      for (unsigned t = 0; t < M; ++t) rank += (wbuf[wid][t] < k0) ? 1 : 0;
      if (rank < Kc) {
        int j = (int)(k0 & 0xffffffffULL);
        float cmj = ((cmw[j>>5] >> (j&31)) & 1) ? 1.f : 0.f;
        float dx = __fsub_rn(xi0, xsx[j]);
        float dy = __fsub_rn(xi1, xsy[j]);
        float dz = __fsub_rn(xi2, xsz[j]);
        float ss2 = __fadd_rn(__fadd_rn(__fmul_rn(dx,dx), __fmul_rn(dy,dy)), __fmul_rn(dz,dz));
        float dist = __fsqrt_rn(__fadd_rn(ss2, 1e-8f));
        float D = __fmul_rn(__fmul_rn(cmi, cmj), dist);
        eix[(size_t)row*Kc + rank] = j;
        ws[WS_EDS + (size_t)row*Kc + rank] = D;
      }
    }
    __builtin_amdgcn_wave_barrier();
  }
}

// ---------------- Kernel D2: S GEMM + fused LayerNorm + conf-RBF -> final ns ------
// 8-row tiles, A k-major stride 8 in LDS, B prefetch. Epilogue: block-reduce
// per-row mean/var, apply LN*g+b + (rbf(conf)@cw + cb). Replaces kln_node.
__global__ __launch_bounds__(256) void kgemm_s(const float* __restrict__ ws,
                                               const float* __restrict__ wsw,
                                               const float* __restrict__ wsb,
                                               const float* __restrict__ rbuf,
                                               const float* __restrict__ lg,
                                               const float* __restrict__ lb,
                                               const float* __restrict__ cw,
                                               const float* __restrict__ cb,
                                               float* __restrict__ out) {
  __shared__ __align__(16) float Ast[SK*8];
  __shared__ float rbs[128];
  __shared__ float rsum[4][8], rsq[4][8];
  int tid = threadIdx.x;
  int lane = tid & 63, wid = tid >> 6;
  int row0 = blockIdx.x * 8;
  if (tid < 128) rbs[tid] = rbuf[(size_t)row0*16 + tid];
  #pragma unroll
  for (int r = 0; r < 8; ++r)
    for (int k = tid; k < SK; k += 256)
      Ast[k*8 + r] = ws[WS_SIN + (size_t)(row0+r)*SK + k];
  __syncthreads();
  float acc[8][4] = {};
  float b0 = wsw[tid], b1 = wsw[tid+256], b2 = wsw[tid+512], b3 = wsw[tid+768];
  for (int k = 0; k < SK-1; ++k) {
    float c0 = b0, c1 = b1, c2 = b2, c3 = b3;
    const float* bp = wsw + (size_t)(k+1)*NSc + tid;
    b0 = bp[0]; b1 = bp[256]; b2 = bp[512]; b3 = bp[768];
    float4 a0 = *(const float4*)&Ast[k*8 + 0];
    float4 a1 = *(const float4*)&Ast[k*8 + 4];
    float av[8] = {a0.x,a0.y,a0.z,a0.w, a1.x,a1.y,a1.z,a1.w};
    #pragma unroll
    for (int r = 0; r < 8; ++r) {
      acc[r][0] = fmaf(av[r], c0, acc[r][0]);
      acc[r][1] = fmaf(av[r], c1, acc[r][1]);
      acc[r][2] = fmaf(av[r], c2, acc[r][2]);
      acc[r][3] = fmaf(av[r], c3, acc[r][3]);
    }
  }
  {
    int k = SK-1;
    float4 a0 = *(const float4*)&Ast[k*8 + 0];
    float4 a1 = *(const float4*)&Ast[k*8 + 4];
    float av[8] = {a0.x,a0.y,a0.z,a0.w, a1.x,a1.y,a1.z,a1.w};
    #pragma unroll
    for (int r = 0; r < 8; ++r) {
      acc[r][0] = fmaf(av[r], b0, acc[r][0]);
      acc[r][1] = fmaf(av[r], b1, acc[r][1]);
      acc[r][2] = fmaf(av[r], b2, acc[r][2]);
      acc[r][3] = fmaf(av[r], b3, acc[r][3]);
    }
  }
  float bb0 = wsb[tid], bb1 = wsb[tid+256], bb2 = wsb[tid+512], bb3 = wsb[tid+768];
  // add bias; per-row partial sums for LN
  #pragma unroll
  for (int r = 0; r < 8; ++r) {
    acc[r][0] += bb0; acc[r][1] += bb1; acc[r][2] += bb2; acc[r][3] += bb3;
    float sm = acc[r][0]+acc[r][1]+acc[r][2]+acc[r][3];
    float sq = acc[r][0]*acc[r][0]+acc[r][1]*acc[r][1]+acc[r][2]*acc[r][2]+acc[r][3]*acc[r][3];
    #pragma unroll
    for (int off = 1; off < 64; off <<= 1) { sm += __shfl_xor(sm, off); sq += __shfl_xor(sq, off); }
    if (lane == 0) { rsum[wid][r] = sm; rsq[wid][r] = sq; }
  }
  __syncthreads();
  float lg_[4] = {lg[tid], lg[tid+256], lg[tid+512], lg[tid+768]};
  float lb_[4] = {lb[tid], lb[tid+256], lb[tid+512], lb[tid+768]};
  #pragma unroll
  for (int r = 0; r < 8; ++r) {
    float sm = rsum[0][r]+rsum[1][r]+rsum[2][r]+rsum[3][r];
    float sq = rsq[0][r]+rsq[1][r]+rsq[2][r]+rsq[3][r];
    float mu = sm * (1.f/1024.f);
    float var = fmaxf(sq * (1.f/1024.f) - mu*mu, 0.f);
    float isd = 1.f / sqrtf(var + 1e-4f);
    const float* rb = &rbs[r*16];
    size_t o = OUT_NS + (size_t)(row0+r)*NSc + tid;
    #pragma unroll
    for (int q = 0; q < 4; ++q) {
      int c = tid + q*256;
      float t = cb[c];
      #pragma unroll
      for (int m = 0; m < 16; ++m) t = fmaf(rb[m], cw[m*1024 + c], t);
      out[o + q*256] = (acc[r][q]-mu)*isd*lg_[q] + lb_[q] + t;
    }
  }
}

// ---------------- Kernel D3: V GEMM fused with vector-norm epilogue --------------
__global__ __launch_bounds__(256) void kgemm_v(const float* __restrict__ avh,
                                               const float* __restrict__ wv,
                                               float* __restrict__ out) {
  __shared__ __align__(16) float Ast[3*256*20];
  int tid = threadIdx.x;
  int lane = tid & 63, rg = tid >> 6;
  int row0 = blockIdx.x * 16;
  int c0 = lane * 4;
  #pragma unroll
  for (int d = 0; d < 3; ++d)
    #pragma unroll
    for (int r = 0; r < 16; ++r)
      Ast[d*5120 + tid*20 + r] = avh[(size_t)d*Nn*256 + (size_t)(row0+r)*256 + tid];
  __syncthreads();
  float acc[4][4][3] = {};   // [row][col][dim]
  int r4 = rg * 4;
  float4 bn = *(const float4*)&wv[c0];
  for (int k = 0; k < 255; ++k) {
    float4 bcur = bn;
    bn = *(const float4*)&wv[(size_t)(k+1)*256 + c0];
    float4 a0 = *(const float4*)&Ast[0*5120 + k*20 + r4];
    float4 a1 = *(const float4*)&Ast[1*5120 + k*20 + r4];
    float4 a2 = *(const float4*)&Ast[2*5120 + k*20 + r4];
    float av0[4] = {a0.x,a0.y,a0.z,a0.w};
    float av1[4] = {a1.x,a1.y,a1.z,a1.w};
    float av2[4] = {a2.x,a2.y,a2.z,a2.w};
    float bv[4] = {bcur.x,bcur.y,bcur.z,bcur.w};
    #pragma unroll
    for (int r = 0; r < 4; ++r)
      #pragma unroll
      for (int q = 0; q < 4; ++q) {
        acc[r][q][0] = fmaf(av0[r], bv[q], acc[r][q][0]);
        acc[r][q][1] = fmaf(av1[r], bv[q], acc[r][q][1]);
        acc[r][q][2] = fmaf(av2[r], bv[q], acc[r][q][2]);
      }
  }
  {
    int k = 255;
    float4 a0 = *(const float4*)&Ast[0*5120 + k*20 + r4];
    float4 a1 = *(const float4*)&Ast[1*5120 + k*20 + r4];
    float4 a2 = *(const float4*)&Ast[2*5120 + k*20 + r4];
    float av0[4] = {a0.x,a0.y,a0.z,a0.w};
    float av1[4] = {a1.x,a1.y,a1.z,a1.w};
    float av2[4] = {a2.x,a2.y,a2.z,a2.w};
    float bv[4] = {bn.x,bn.y,bn.z,bn.w};
    #pragma unroll
    for (int r = 0; r < 4; ++r)
      #pragma unroll
      for (int q = 0; q < 4; ++q) {
        acc[r][q][0] = fmaf(av0[r], bv[q], acc[r][q][0]);
        acc[r][q][1] = fmaf(av1[r], bv[q], acc[r][q][1]);
        acc[r][q][2] = fmaf(av2[r], bv[q], acc[r][q][2]);
      }
  }
  #pragma unroll
  for (int r = 0; r < 4; ++r) {
    float p = 0.f;
    #pragma unroll
    for (int q = 0; q < 4; ++q) {
      float s2 = acc[r][q][0]*acc[r][q][0] + acc[r][q][1]*acc[r][q][1] + acc[r][q][2]*acc[r][q][2];
      p += fmaxf(s2, 1e-8f);
    }
    #pragma unroll
    for (int off = 1; off < 64; off <<= 1) p += __shfl_xor(p, off);
    float isd = 1.f / sqrtf(p * (1.f/256.f));
    int row = row0 + r4 + r;
    size_t o = OUT_NV + (size_t)row*768 + (size_t)c0*3;
    float4 f0 = {acc[r][0][0]*isd, acc[r][0][1]*isd, acc[r][0][2]*isd, acc[r][1][0]*isd};
    float4 f1 = {acc[r][1][1]*isd, acc[r][1][2]*isd, acc[r][2][0]*isd, acc[r][2][1]*isd};
    float4 f2 = {acc[r][2][2]*isd, acc[r][3][0]*isd, acc[r][3][1]*isd, acc[r][3][2]*isd};
    *(float4*)&out[o+0] = f0;
    *(float4*)&out[o+4] = f1;
    *(float4*)&out[o+8] = f2;
  }
}

// ---------------- Kernel C: edge features + edge GVP + edge LN + ei ----------------
__global__ __launch_bounds__(256) void kedge(const float* __restrict__ coords,
    const int* __restrict__ resid,
    const float* __restrict__ ewh, const float* __restrict__ eww,
    const float* __restrict__ ewb, const float* __restrict__ ewv,
    const float* __restrict__ elg, const float* __restrict__ elb,
    const float* __restrict__ ws, float* __restrict__ out) {
  __shared__ float w[35*32];
  __shared__ float wb[32], g[32], bb[32];
  int tid = threadIdx.x;
  for (int t = tid; t < 35*32; t += 256) w[t] = eww[t];
  if (tid < 32) { wb[tid] = ewb[tid]; g[tid] = elg[tid]; bb[tid] = elb[tid]; }
  __syncthreads();
  int e = blockIdx.x * 256 + tid;
  if (e >= NEc) return;
  int b = e / (Lc*Kc);
  int rem = e - b*(Lc*Kc);
  int i = rem / Kc;
  int row = b*Lc + i;
  const int* eix = (const int*)(ws + WS_EIX);
  int j = eix[e];
  float Dn = ws[WS_EDS + e];
  bool jok = ((unsigned)j < (unsigned)Lc);
  bool valid = jok && (Dn < 5e7f) && (Dn < 5e9f);
  if (!valid) {
    #pragma unroll
    for (int c = 0; c < 32; ++c) out[OUT_ES + (size_t)e*32 + c] = 0.f;
    out[OUT_EV + (size_t)e*3 + 0] = 0.f;
    out[OUT_EV + (size_t)e*3 + 1] = 0.f;
    out[OUT_EV + (size_t)e*3 + 2] = 0.f;
    out[OUT_EI + e]       = -1.f;
    out[OUT_EI + NEc + e] = -1.f;
    return;
  }
  int dcl = resid[row] - resid[b*Lc + j];
  dcl = dcl < -32 ? -32 : (dcl > 32 ? 32 : dcl);
  float dpos = (float)dcl;
  float s[35];
  #pragma unroll
  for (int m = 0; m < 16; ++m) {
    float c = (20.f/15.f) * (float)m;
    float z = (Dn - c) * 0.8f;
    s[m] = expf(-z*z);
  }
  #pragma unroll
  for (int m = 0; m < 8; ++m) {
    float fr = expf((float)(2*m) * (-0.57564627324851148f));
    float ang = dpos * fr;
    s[16+m] = cosf(ang);
    s[24+m] = sinf(ang);
  }
  float csf = ws[WS_CMF + row];
  float cdf = ws[WS_CMF + b*Lc + j];
  s[32] = 1.f - csf; s[33] = 1.f - cdf;
  const float* Xb = coords + (size_t)b*Lc*9;
  float vx = Xb[i*9+3] - Xb[j*9+3];
  float vy = Xb[i*9+4] - Xb[j*9+4];
  float vz = Xb[i*9+5] - Xb[j*9+5];
  float ss2 = vx*vx + vy*vy + vz*vz;
  float inv = 1.f / sqrtf(ss2 + 1e-8f);
  float e0 = vx*inv, e1 = vy*inv, e2 = vz*inv;
  if (!isfinite(e0)) e0 = 0.f;
  if (!isfinite(e1)) e1 = 0.f;
  if (!isfinite(e2)) e2 = 0.f;
  float wh00 = ewh[0], wv00 = ewv[0];
  float vh0 = e0*wh00, vh1 = e1*wh00, vh2 = e2*wh00;
  s[34] = sqrtf(fmaxf(vh0*vh0 + vh1*vh1 + vh2*vh2, 1e-8f));
  float o[32]; float sm = 0.f;
  #pragma unroll
  for (int c = 0; c < 32; ++c) {
    float a = wb[c];
    #pragma unroll
    for (int q = 0; q < 35; ++q) a = fmaf(s[q], w[q*32 + c], a);
    o[c] = a; sm += a;
  }
  float mu = sm * (1.f/32.f);
  float sq = 0.f;
  #pragma unroll
  for (int c = 0; c < 32; ++c) { float dd = o[c]-mu; sq += dd*dd; }
  float isd = 1.f / sqrtf(sq*(1.f/32.f) + 1e-4f);
  float vo0 = vh0*wv00, vo1 = vh1*wv00, vo2 = vh2*wv00;
  float vn2 = fmaxf(vo0*vo0 + vo1*vo1 + vo2*vo2, 1e-8f);
  float ivn = 1.f / sqrtf(vn2);
  #pragma unroll
  for (int c = 0; c < 32; ++c)
    out[OUT_ES + (size_t)e*32 + c] = (o[c]-mu)*isd*g[c] + bb[c];
  out[OUT_EV + (size_t)e*3 + 0] = vo0*ivn;
  out[OUT_EV + (size_t)e*3 + 1] = vo1*ivn;
  out[OUT_EV + (size_t)e*3 + 2] = vo2*ivn;
  out[OUT_EI + e]       = (float)row;
  out[OUT_EI + NEc + e] = (float)(b*Lc + j);
}

extern "C" void kernel_launch(void* const* d_in, const int* in_sizes, int n_in,
                              void* d_out, int out_size, void* d_ws, size_t ws_size,
                              hipStream_t stream) {
  const float* coords         = (const float*)d_in[0];
  const unsigned char* cmask  = (const unsigned char*)d_in[1];
  const int* resid            = (const int*)d_in[2];
  const unsigned char* pmask  = (const unsigned char*)d_in[3];
  const float* conf           = (const float*)d_in[4];
  const float* nwh            = (const float*)d_in[5];
  const float* nww            = (const float*)d_in[6];
  const float* nwb            = (const float*)d_in[7];
  const float* nwv            = (const float*)d_in[8];
  const float* nlg            = (const float*)d_in[9];
  const float* nlb            = (const float*)d_in[10];
  const float* ewh            = (const float*)d_in[11];
  const float* eww            = (const float*)d_in[12];
  const float* ewb            = (const float*)d_in[13];
  const float* ewv            = (const float*)d_in[14];
  const float* elg            = (const float*)d_in[15];
  const float* elb            = (const float*)d_in[16];
  const float* cw             = (const float*)d_in[17];
  const float* cb             = (const float*)d_in[18];
  float* out = (float*)d_out;
  float* ws  = (float*)d_ws;
  float* avh  = out + OUT_ES;  // stage vh in es region; consumed by kgemm_v before kedge writes es
  float* rbuf = out + OUT_EV;  // stage rbf(conf) in ev region; consumed by kgemm_s before kedge writes ev

  kmask<<<Nn/256, 256, 0, stream>>>(cmask, ws);
  knode_geom<<<(Nn+255)/256, 256, 0, stream>>>(coords, ws);
  kgvp_pre<<<Nn, 256, 0, stream>>>(ws, nwh, conf, avh, rbuf);
  ktopk<<<Nn/8, 256, 0, stream>>>(coords, resid, pmask, ws);
  kgemm_s<<<Nn/8, 256, 0, stream>>>(ws, nww, nwb, rbuf, nlg, nlb, cw, cb, out);
  kgemm_v<<<Nn/16, 256, 0, stream>>>(avh, nwv, out);
  kedge<<<NEc/256, 256, 0, stream>>>(coords, resid, ewh, eww, ewb, ewv, elg, elb, ws, out);
}